// Round 1
// baseline (4400.438 us; speedup 1.0000x reference)
//
#include <hip/hip_runtime.h>

// Problem constants
constexpr int Hh = 256, Ww = 256, HW = Hh * Ww;
constexpr int Bb = 2, Cc = 64, Pp = 3, NOo = 16, FEXc = 48, Nn = 32768;

// ---------------- mask weight: wm = mask / max(avg3x3(mask), 1e-8) ----------------
__global__ __launch_bounds__(256) void k_wm(const float* __restrict__ mask,
                                            float* __restrict__ wm) {
    int pos = blockIdx.x * 256 + threadIdx.x;
    int h = pos >> 8, w = pos & 255;
    float s = 0.f;
    #pragma unroll
    for (int dy = -1; dy <= 1; ++dy)
        #pragma unroll
        for (int dx = -1; dx <= 1; ++dx) {
            int hh = h + dy, ww = w + dx;
            if (hh >= 0 && hh < Hh && ww >= 0 && ww < Ww) s += mask[hh * Ww + ww];
        }
    float avg = s * (1.f / 9.f);
    wm[pos] = mask[pos] / fmaxf(avg, 1e-8f);
}

// ---------------- A = mask * xs[i] ----------------
__global__ __launch_bounds__(256) void k_maskmul(const float4* __restrict__ xs,
                                                 const float4* __restrict__ mask,
                                                 float4* __restrict__ out) {
    int i = blockIdx.x * 256 + threadIdx.x;          // over B*C*HW/4
    int pos4 = i & (HW / 4 - 1);
    float4 mk = mask[pos4];
    float4 x = xs[i];
    out[i] = make_float4(mk.x * x.x, mk.y * x.y, mk.z * x.z, mk.w * x.w);
}

// ---------------- zero a float4 buffer ----------------
__global__ __launch_bounds__(256) void k_zero(float4* __restrict__ p) {
    p[blockIdx.x * 256 + threadIdx.x] = make_float4(0.f, 0.f, 0.f, 0.f);
}

// ---------------- direct 3x3 conv, SAME padding, fused epilogue ----------------
// MODE 0: out = relu(conv*wm)   MODE 1: out = base + conv*wm   MODE 2: out = conv*wm
constexpr int TW = 32, TH = 8, CK = 16;   // spatial tile 32x8, 16-channel LDS chunks

template <int CIN, int OCH, int MODE>
__global__ __launch_bounds__(256) void k_conv(
    const float* __restrict__ in,    // (B, CIN, H, W)
    const float* __restrict__ wgt,   // (nOC*OCH, CIN, 3, 3)
    const float* __restrict__ wm,    // (HW)
    const float* base,               // (B, outCtot, H, W)  [MODE 1]  (may alias out)
    float* out,                      // (B, outCtot, H, W)
    int nOC, int outCtot, int outCbase0) {
    __shared__ float lds[CK * 10 * 34];
    const int tid = threadIdx.x;
    const int tx = tid & 31, ty = tid >> 5;
    const int w0 = blockIdx.x * TW, h0 = blockIdx.y * TH;
    const int zz = blockIdx.z;
    const int b = zz / nOC;
    const int chunk = zz - b * nOC;

    float acc[OCH];
    #pragma unroll
    for (int o = 0; o < OCH; ++o) acc[o] = 0.f;

    for (int ck = 0; ck < CIN / CK; ++ck) {
        __syncthreads();
        // stage CK channels of the 10x34 halo tile
        for (int idx = tid; idx < CK * 340; idx += 256) {
            int c = idx / 340;
            int rr = idx - c * 340;
            int r = rr / 34;
            int col = rr - r * 34;
            int gh = h0 + r - 1, gw = w0 + col - 1;
            float v = 0.f;
            if (gh >= 0 && gh < Hh && gw >= 0 && gw < Ww)
                v = in[(b * CIN + ck * CK + c) * HW + gh * Ww + gw];
            lds[idx] = v;
        }
        __syncthreads();

        #pragma unroll 2
        for (int c = 0; c < CK; ++c) {
            float nb[9];
            #pragma unroll
            for (int dy = 0; dy < 3; ++dy)
                #pragma unroll
                for (int dx = 0; dx < 3; ++dx)
                    nb[dy * 3 + dx] = lds[c * 340 + (ty + dy) * 34 + tx + dx];
            // weight index is wave-uniform -> scalar loads
            const float* wp = wgt + ((chunk * OCH) * CIN + ck * CK + c) * 9;
            #pragma unroll
            for (int o = 0; o < OCH; ++o) {
                #pragma unroll
                for (int k = 0; k < 9; ++k)
                    acc[o] += nb[k] * wp[o * CIN * 9 + k];
            }
        }
    }

    const int pos = (h0 + ty) * Ww + w0 + tx;
    const float wmv = wm[pos];
    const int ocg = outCbase0 + chunk * OCH;
    #pragma unroll
    for (int o = 0; o < OCH; ++o) {
        float v = acc[o] * wmv;
        int oidx = (b * outCtot + ocg + o) * HW + pos;
        if (MODE == 0)      out[oidx] = fmaxf(v, 0.f);
        else if (MODE == 1) out[oidx] = base[oidx] + v;
        else                out[oidx] = v;
    }
}

// ---------------- gather f=F+G at yi, dsda, MLP 49->48->48->3, scatter to dense pvd ----------------
__global__ __launch_bounds__(256) void k_gather_mlp(
    const float* __restrict__ F, const float* __restrict__ G,
    const int* __restrict__ yi, const float* __restrict__ m,
    const float* __restrict__ w1, const float* __restrict__ b1,
    const float* __restrict__ w2, const float* __restrict__ b2,
    const float* __restrict__ w3, const float* __restrict__ b3,
    float* __restrict__ pvd) {
    int t = blockIdx.x * 256 + threadIdx.x;   // over B*N
    int b = t >> 15;            // N = 32768
    int n = t & (Nn - 1);
    int pos = yi[n];

    float h[FEXc + 1];
    #pragma unroll
    for (int c = 0; c < FEXc; ++c) {
        int idx = (b * FEXc + c) * HW + pos;
        h[c] = F[idx] + G[idx];
    }
    {   // dsda (wave-uniform m, per-lane pos)
        float det = m[0] * (m[4] * m[8] - m[5] * m[7])
                  - m[1] * (m[3] * m[8] - m[5] * m[6])
                  + m[2] * (m[3] * m[7] - m[4] * m[6]);
        int yr = pos >> 8, xc = pos & 255;
        float wc = m[6] * (float)xc + m[7] * (float)yr + m[8];
        float cw = fmaxf(fabsf(wc), 1e-8f);
        float dsda = fabsf(det) / (cw * cw * cw);
        h[FEXc] = logf(dsda + 1e-8f);
    }

    float h1[FEXc];
    #pragma unroll
    for (int o = 0; o < FEXc; ++o) {
        float a = b1[o];
        #pragma unroll
        for (int c = 0; c < FEXc + 1; ++c) a += w1[o * (FEXc + 1) + c] * h[c];
        h1[o] = fmaxf(a, 0.f);
    }
    float h2[FEXc];
    #pragma unroll
    for (int o = 0; o < FEXc; ++o) {
        float a = b2[o];
        #pragma unroll
        for (int c = 0; c < FEXc; ++c) a += w2[o * FEXc + c] * h1[c];
        h2[o] = fmaxf(a, 0.f);
    }
    #pragma unroll
    for (int p = 0; p < Pp; ++p) {
        float a = b3[p];
        #pragma unroll
        for (int c = 0; c < FEXc; ++c) a += w3[p * FEXc + c] * h2[c];
        pvd[(b * Pp + p) * HW + pos] = a;
    }
}

// ---------------- out[b,c,pos] = sum_p pvd[b,p,pos] * xs[p,b,c,pos] ----------------
__global__ __launch_bounds__(256) void k_blend(const float4* __restrict__ xs,
                                               const float4* __restrict__ pvd,
                                               float4* __restrict__ out) {
    int i = blockIdx.x * 256 + threadIdx.x;   // over B*C*HW/4
    int pos4 = i & (HW / 4 - 1);
    int bc = i >> 14;                          // / (HW/4)
    int b = bc >> 6;                           // / C
    float4 acc = make_float4(0.f, 0.f, 0.f, 0.f);
    #pragma unroll
    for (int p = 0; p < Pp; ++p) {
        float4 pv = pvd[(b * Pp + p) * (HW / 4) + pos4];
        float4 x = xs[p * (Bb * Cc * HW / 4) + i];
        acc.x += pv.x * x.x;
        acc.y += pv.y * x.y;
        acc.z += pv.z * x.z;
        acc.w += pv.w * x.w;
    }
    out[i] = acc;
}

extern "C" void kernel_launch(void* const* d_in, const int* in_sizes, int n_in,
                              void* d_out, int out_size, void* d_ws, size_t ws_size,
                              hipStream_t stream) {
    const float* xs        = (const float*)d_in[0];
    const float* mask      = (const float*)d_in[1];
    const int*   yi        = (const int*)d_in[2];
    const float* m         = (const float*)d_in[3];
    const float* ss_res_w  = (const float*)d_in[4];
    const float* ss_out_w  = (const float*)d_in[5];
    const float* feat_res_w= (const float*)d_in[6];
    const float* w1 = (const float*)d_in[7];
    const float* b1 = (const float*)d_in[8];
    const float* w2 = (const float*)d_in[9];
    const float* b2 = (const float*)d_in[10];
    const float* w3 = (const float*)d_in[11];
    const float* b3 = (const float*)d_in[12];

    // workspace layout (floats): wm | A (B*64*HW) | F (B*48*HW) | pvd (B*3*HW)
    float* ws  = (float*)d_ws;
    float* wm  = ws;
    float* A   = ws + HW;
    float* F   = A + Bb * Cc * HW;
    float* pvd = F + Bb * FEXc * HW;
    float* Bf  = (float*)d_out;   // scratch; fully rewritten by k_blend at the end

    k_wm<<<HW / 256, 256, 0, stream>>>(mask, wm);

    const dim3 g64(8, 32, Bb * 2);   // 64 out ch in 2 chunks of 32
    const dim3 g16(8, 32, Bb * 1);   // 16 out ch in 1 chunk
    const dim3 g48(8, 32, Bb * 2);   // 48 out ch in 2 chunks of 24

    for (int i = 0; i < Pp; ++i) {
        k_maskmul<<<Bb * Cc * HW / 4 / 256, 256, 0, stream>>>(
            (const float4*)(xs + (size_t)i * Bb * Cc * HW), (const float4*)mask, (float4*)A);
        const float* wr = ss_res_w + (size_t)i * 4 * Cc * Cc * 9;
        k_conv<64, 32, 0><<<g64, 256, 0, stream>>>(A,  wr,                 wm, nullptr, Bf, 2, 64, 0);
        k_conv<64, 32, 1><<<g64, 256, 0, stream>>>(Bf, wr + 1 * Cc * Cc * 9, wm, A, A,   2, 64, 0);
        k_conv<64, 32, 0><<<g64, 256, 0, stream>>>(A,  wr + 2 * Cc * Cc * 9, wm, nullptr, Bf, 2, 64, 0);
        k_conv<64, 32, 1><<<g64, 256, 0, stream>>>(Bf, wr + 3 * Cc * Cc * 9, wm, A, A,   2, 64, 0);
        k_conv<64, 16, 2><<<g16, 256, 0, stream>>>(A,  ss_out_w + (size_t)i * NOo * Cc * 9,
                                                   wm, nullptr, F, 1, 48, i * NOo);
    }

    float* G = A;   // A free after pyramids; reuse as trunk accumulator
    const int FW = FEXc * FEXc * 9;
    k_conv<48, 24, 0><<<g48, 256, 0, stream>>>(F,  feat_res_w,          wm, nullptr, Bf, 2, 48, 0);
    k_conv<48, 24, 1><<<g48, 256, 0, stream>>>(Bf, feat_res_w + 1 * FW, wm, F, G,    2, 48, 0);
    k_conv<48, 24, 0><<<g48, 256, 0, stream>>>(G,  feat_res_w + 2 * FW, wm, nullptr, Bf, 2, 48, 0);
    k_conv<48, 24, 1><<<g48, 256, 0, stream>>>(Bf, feat_res_w + 3 * FW, wm, G, G,    2, 48, 0);

    k_zero<<<Bb * Pp * HW / 4 / 256, 256, 0, stream>>>((float4*)pvd);
    k_gather_mlp<<<Bb * Nn / 256, 256, 0, stream>>>(F, G, yi, m, w1, b1, w2, b2, w3, b3, pvd);
    k_blend<<<Bb * Cc * HW / 4 / 256, 256, 0, stream>>>((const float4*)xs, (const float4*)pvd,
                                                        (float4*)d_out);
}

// Round 2
// 1183.591 us; speedup vs baseline: 3.7179x; 3.7179x over previous
//
#include <hip/hip_runtime.h>
#include <hip/hip_bf16.h>

typedef unsigned short ushort_t;
typedef __attribute__((ext_vector_type(8))) short short8;
typedef __attribute__((ext_vector_type(4))) float f32x4;

// Problem constants
constexpr int Hh = 256, Ww = 256, HW = Hh * Ww;
constexpr int Bb = 2, Cc = 64, Pp = 3, NOo = 16, FEXc = 48, Nn = 32768;
constexpr int TW = 32, TH = 8;       // spatial tile per block
constexpr int PADC = 72;             // LDS pixel stride (channels, bf16) -> 144B, 16B-aligned, 2-way bank alias (free)
constexpr int HALO = 340;            // 34 x 10 halo pixels

__device__ inline ushort_t f2bf(float v) {
    __hip_bfloat16 h = __float2bfloat16(v);
    return *(ushort_t*)&h;
}
__device__ inline float bf2f(ushort_t u) {
    __hip_bfloat16 h = *(__hip_bfloat16*)&u;
    return __bfloat162float(h);
}

// ---------------- mask weight: wm = mask / max(avg3x3(mask), 1e-8) ----------------
__global__ __launch_bounds__(256) void k_wm(const float* __restrict__ mask,
                                            float* __restrict__ wm) {
    int pos = blockIdx.x * 256 + threadIdx.x;
    int h = pos >> 8, w = pos & 255;
    float s = 0.f;
    #pragma unroll
    for (int dy = -1; dy <= 1; ++dy)
        #pragma unroll
        for (int dx = -1; dx <= 1; ++dx) {
            int hh = h + dy, ww = w + dx;
            if (hh >= 0 && hh < Hh && ww >= 0 && ww < Ww) s += mask[hh * Ww + ww];
        }
    float avg = s * (1.f / 9.f);
    wm[pos] = mask[pos] / fmaxf(avg, 1e-8f);
}

// ---------------- zero a float4 buffer ----------------
__global__ __launch_bounds__(256) void k_zero(float4* __restrict__ p) {
    p[blockIdx.x * 256 + threadIdx.x] = make_float4(0.f, 0.f, 0.f, 0.f);
}

// ---------------- weight transforms: fp32 [oc][cin][3][3] -> bf16 [tap][oc][c64] ----
__global__ __launch_bounds__(256) void k_wx_res(const float* __restrict__ src,
                                                ushort_t* __restrict__ dst) {
    int idx = blockIdx.x * 256 + threadIdx.x;          // < 12*9*64*64 = 442368
    int j = idx / 36864; int rem = idx - j * 36864;
    int t = rem >> 12; int o = (rem >> 6) & 63; int c = rem & 63;
    dst[idx] = f2bf(src[j * 36864 + o * 576 + c * 9 + t]);
}
__global__ __launch_bounds__(256) void k_wx_out(const float* __restrict__ src,
                                                ushort_t* __restrict__ dst) {
    int idx = blockIdx.x * 256 + threadIdx.x;          // < 3*9*16*64 = 27648
    int i = idx / 9216; int rem = idx - i * 9216;
    int t = rem >> 10; int o = (rem >> 6) & 15; int c = rem & 63;
    dst[idx] = f2bf(src[i * 9216 + o * 576 + c * 9 + t]);
}
__global__ __launch_bounds__(256) void k_wx_trunk(const float* __restrict__ src,
                                                  ushort_t* __restrict__ dst) {
    int idx = blockIdx.x * 256 + threadIdx.x;          // < 4*9*48*64 = 110592
    int j = idx / 27648; int rem = idx - j * 27648;
    int t = rem / 3072; int rem2 = rem - t * 3072;
    int o = rem2 >> 6; int c = rem2 & 63;
    float v = (c < 48) ? src[j * (48 * 48 * 9) + o * 432 + c * 9 + t] : 0.f;
    dst[idx] = f2bf(v);
}

// ---------------- MFMA implicit-GEMM 3x3 conv ----------------
// MODE 0: out = relu(conv*wm)              (bf16 store)
// MODE 1: out = bf16(base) + conv*wm       (base bf16, may alias out)
// MODE 2: out = conv*wm
// MODE 3: out = mask*basef32 + conv*wm     (base fp32, e.g. xs slice)
template <int OC, int MODE, bool INF32, bool MASKIN>
__global__ __launch_bounds__(256) void k_mconv(
    const void* __restrict__ in_,          // (B,64,HW) bf16, or fp32 if INF32
    const ushort_t* __restrict__ wB,       // [9][OC][64] bf16
    const float* __restrict__ wm,
    const float* __restrict__ mask,
    const void* __restrict__ base_,        // per MODE
    ushort_t* __restrict__ out,            // (B,outCtot,HW) bf16
    int outCtot, int outCbase) {
    constexpr int NM = OC / 16;
    __shared__ __align__(16) ushort_t lds[HALO * PADC];
    const int tid = threadIdx.x;
    const int w0 = blockIdx.x * TW, h0 = blockIdx.y * TH;
    const int b = blockIdx.z;

    // ---- stage all 64 input channels of the 34x10 halo tile as bf16 [pixel][chan] ----
    {
        const float* inf = (const float*)in_;
        const ushort_t* inb = (const ushort_t*)in_;
        int c = 0, pp = tid;                      // tid < 340 so c=0 initially
        for (int k = 0; k < (HALO * 64) / 256; ++k) {
            int r = (pp * 241) >> 13;             // pp/34 for pp<340
            int col = pp - r * 34;
            int gh = h0 + r - 1, gw = w0 + col - 1;
            bool ok = (gh >= 0 && gh < Hh && gw >= 0 && gw < Ww);
            int gpos = gh * Ww + gw;
            size_t goff = (size_t)(b * 64 + c) * HW + gpos;
            ushort_t uv;
            if (INF32) {
                float v = ok ? inf[goff] : 0.f;
                if (MASKIN && ok) v *= mask[gpos];
                uv = f2bf(v);
            } else {
                uv = ok ? inb[goff] : (ushort_t)0;
            }
            lds[pp * PADC + c] = uv;
            pp += 256;
            if (pp >= HALO) { pp -= HALO; c++; }
        }
    }
    __syncthreads();

    const int wv = tid >> 6;                  // wave 0..3 -> rows 2w,2w+1
    const int l = tid & 63;
    const int lo = l & 15, g8 = (l >> 4) * 8;

    f32x4 acc[NM][4];
    #pragma unroll
    for (int mf = 0; mf < NM; ++mf)
        #pragma unroll
        for (int nf = 0; nf < 4; ++nf) acc[mf][nf] = (f32x4){0.f, 0.f, 0.f, 0.f};

    #pragma unroll
    for (int dy = 0; dy < 3; ++dy)
        #pragma unroll
        for (int dx = 0; dx < 3; ++dx)
            #pragma unroll
            for (int ck = 0; ck < 2; ++ck) {
                const int t = dy * 3 + dx;
                short8 bfr[4];
                #pragma unroll
                for (int nf = 0; nf < 4; ++nf) {
                    int hr = 2 * wv + (nf >> 1) + dy;         // halo row
                    int hc = (nf & 1) * 16 + lo + dx;          // halo col
                    bfr[nf] = *(const short8*)&lds[(hr * 34 + hc) * PADC + ck * 32 + g8];
                }
                short8 afr[NM];
                #pragma unroll
                for (int mf = 0; mf < NM; ++mf)
                    afr[mf] = *(const short8*)&wB[((t * OC + mf * 16 + lo) * 64) + ck * 32 + g8];
                #pragma unroll
                for (int mf = 0; mf < NM; ++mf)
                    #pragma unroll
                    for (int nf = 0; nf < 4; ++nf)
                        acc[mf][nf] = __builtin_amdgcn_mfma_f32_16x16x32_bf16(
                            afr[mf], bfr[nf], acc[mf][nf], 0, 0, 0);
            }

    // ---- epilogue: C[m][n] layout col=lane&15 (pixel), row=(lane>>4)*4+j (outch) ----
    const float* basef = (const float*)base_;
    const ushort_t* baseb = (const ushort_t*)base_;
    #pragma unroll
    for (int nf = 0; nf < 4; ++nf) {
        int r = h0 + 2 * wv + (nf >> 1);
        int x = w0 + (nf & 1) * 16 + lo;
        int pos = r * Ww + x;
        float wmv = wm[pos];
        float mv = (MODE == 3) ? mask[pos] : 0.f;
        #pragma unroll
        for (int mf = 0; mf < NM; ++mf) {
            #pragma unroll
            for (int j = 0; j < 4; ++j) {
                int o = outCbase + mf * 16 + (l >> 4) * 4 + j;
                size_t oidx = (size_t)(b * outCtot + o) * HW + pos;
                float v = acc[mf][nf][j] * wmv;
                if (MODE == 0) v = fmaxf(v, 0.f);
                else if (MODE == 1) v += bf2f(baseb[oidx]);
                else if (MODE == 3) v += mv * basef[oidx];
                out[oidx] = f2bf(v);
            }
        }
    }
}

// ---------------- gather f=F+G at yi, dsda, MLP 49->48->48->3, scatter to dense pvd ----
__global__ __launch_bounds__(256) void k_gather_mlp(
    const ushort_t* __restrict__ F, const ushort_t* __restrict__ G,
    const int* __restrict__ yi, const float* __restrict__ m,
    const float* __restrict__ w1, const float* __restrict__ b1,
    const float* __restrict__ w2, const float* __restrict__ b2,
    const float* __restrict__ w3, const float* __restrict__ b3,
    float* __restrict__ pvd) {
    int t = blockIdx.x * 256 + threadIdx.x;   // over B*N
    int b = t >> 15;
    int n = t & (Nn - 1);
    int pos = yi[n];

    float h[FEXc + 1];
    #pragma unroll
    for (int c = 0; c < FEXc; ++c) {
        size_t idx = (size_t)(b * 64 + c) * HW + pos;
        h[c] = bf2f(F[idx]) + bf2f(G[idx]);
    }
    {
        float det = m[0] * (m[4] * m[8] - m[5] * m[7])
                  - m[1] * (m[3] * m[8] - m[5] * m[6])
                  + m[2] * (m[3] * m[7] - m[4] * m[6]);
        int yr = pos >> 8, xc = pos & 255;
        float wc = m[6] * (float)xc + m[7] * (float)yr + m[8];
        float cw = fmaxf(fabsf(wc), 1e-8f);
        float dsda = fabsf(det) / (cw * cw * cw);
        h[FEXc] = logf(dsda + 1e-8f);
    }

    float h1[FEXc];
    #pragma unroll
    for (int o = 0; o < FEXc; ++o) {
        float a = b1[o];
        #pragma unroll
        for (int c = 0; c < FEXc + 1; ++c) a += w1[o * (FEXc + 1) + c] * h[c];
        h1[o] = fmaxf(a, 0.f);
    }
    float h2[FEXc];
    #pragma unroll
    for (int o = 0; o < FEXc; ++o) {
        float a = b2[o];
        #pragma unroll
        for (int c = 0; c < FEXc; ++c) a += w2[o * FEXc + c] * h1[c];
        h2[o] = fmaxf(a, 0.f);
    }
    #pragma unroll
    for (int p = 0; p < Pp; ++p) {
        float a = b3[p];
        #pragma unroll
        for (int c = 0; c < FEXc; ++c) a += w3[p * FEXc + c] * h2[c];
        pvd[(size_t)(b * Pp + p) * HW + pos] = a;
    }
}

// ---------------- out[b,c,pos] = sum_p pvd[b,p,pos] * xs[p,b,c,pos] ----------------
__global__ __launch_bounds__(256) void k_blend(const float4* __restrict__ xs,
                                               const float4* __restrict__ pvd,
                                               float4* __restrict__ out) {
    int i = blockIdx.x * 256 + threadIdx.x;   // over B*C*HW/4
    int pos4 = i & (HW / 4 - 1);
    int bc = i >> 14;
    int b = bc >> 6;
    float4 acc = make_float4(0.f, 0.f, 0.f, 0.f);
    #pragma unroll
    for (int p = 0; p < Pp; ++p) {
        float4 pv = pvd[(b * Pp + p) * (HW / 4) + pos4];
        float4 x = xs[p * (Bb * Cc * HW / 4) + i];
        acc.x += pv.x * x.x;
        acc.y += pv.y * x.y;
        acc.z += pv.z * x.z;
        acc.w += pv.w * x.w;
    }
    out[i] = acc;
}

extern "C" void kernel_launch(void* const* d_in, const int* in_sizes, int n_in,
                              void* d_out, int out_size, void* d_ws, size_t ws_size,
                              hipStream_t stream) {
    const float* xs        = (const float*)d_in[0];
    const float* mask      = (const float*)d_in[1];
    const int*   yi        = (const int*)d_in[2];
    const float* m         = (const float*)d_in[3];
    const float* ss_res_w  = (const float*)d_in[4];
    const float* ss_out_w  = (const float*)d_in[5];
    const float* feat_res_w= (const float*)d_in[6];
    const float* w1 = (const float*)d_in[7];
    const float* b1 = (const float*)d_in[8];
    const float* w2 = (const float*)d_in[9];
    const float* b2 = (const float*)d_in[10];
    const float* w3 = (const float*)d_in[11];
    const float* b3 = (const float*)d_in[12];

    // workspace: wm f32 | pvd f32 | wB bf16 | A bf16 | F bf16 | G bf16   (~53.3 MB)
    float* wm  = (float*)d_ws;
    float* pvd = wm + HW;
    ushort_t* wB = (ushort_t*)(pvd + (size_t)Bb * Pp * HW);
    constexpr size_t RES_T = 12 * 9 * 64 * 64;     // 442368
    constexpr size_t OUT_T = 3 * 9 * 16 * 64;      // 27648
    constexpr size_t TRK_T = 4 * 9 * 48 * 64;      // 110592
    ushort_t* A = wB + RES_T + OUT_T + TRK_T;
    ushort_t* F = A + (size_t)Bb * 64 * HW;
    ushort_t* G = F + (size_t)Bb * 64 * HW;
    ushort_t* Bf = (ushort_t*)d_out;               // bf16 scratch; rewritten fp32 by k_blend

    k_wm<<<HW / 256, 256, 0, stream>>>(mask, wm);
    k_wx_res  <<<RES_T / 256, 256, 0, stream>>>(ss_res_w, wB);
    k_wx_out  <<<OUT_T / 256, 256, 0, stream>>>(ss_out_w, wB + RES_T);
    k_wx_trunk<<<TRK_T / 256, 256, 0, stream>>>(feat_res_w, wB + RES_T + OUT_T);

    const dim3 grid(Ww / TW, Hh / TH, Bb);         // (8, 32, 2)
    for (int i = 0; i < Pp; ++i) {
        const float* xsi = xs + (size_t)i * Bb * Cc * HW;
        const ushort_t* rw = wB + (size_t)i * 4 * 9 * 64 * 64;
        const ushort_t* ow = wB + RES_T + (size_t)i * 9 * 16 * 64;
        k_mconv<64, 0, true,  true ><<<grid, 256, 0, stream>>>(xsi, rw,              wm, mask, nullptr, Bf, 64, 0);
        k_mconv<64, 3, false, false><<<grid, 256, 0, stream>>>(Bf,  rw + 1 * 36864,  wm, mask, xsi,     A,  64, 0);
        k_mconv<64, 0, false, false><<<grid, 256, 0, stream>>>(A,   rw + 2 * 36864,  wm, mask, nullptr, Bf, 64, 0);
        k_mconv<64, 1, false, false><<<grid, 256, 0, stream>>>(Bf,  rw + 3 * 36864,  wm, mask, A,       A,  64, 0);
        k_mconv<16, 2, false, false><<<grid, 256, 0, stream>>>(A,   ow,              wm, mask, nullptr, F,  64, i * NOo);
    }
    const ushort_t* tw = wB + RES_T + OUT_T;
    k_mconv<48, 0, false, false><<<grid, 256, 0, stream>>>(F,  tw,             wm, mask, nullptr, Bf, 64, 0);
    k_mconv<48, 1, false, false><<<grid, 256, 0, stream>>>(Bf, tw + 1 * 27648, wm, mask, F,       G,  64, 0);
    k_mconv<48, 0, false, false><<<grid, 256, 0, stream>>>(G,  tw + 2 * 27648, wm, mask, nullptr, Bf, 64, 0);
    k_mconv<48, 1, false, false><<<grid, 256, 0, stream>>>(Bf, tw + 3 * 27648, wm, mask, G,       G,  64, 0);

    k_zero<<<(Bb * Pp * HW / 4) / 256, 256, 0, stream>>>((float4*)pvd);
    k_gather_mlp<<<Bb * Nn / 256, 256, 0, stream>>>(F, G, yi, m, w1, b1, w2, b2, w3, b3, pvd);
    k_blend<<<(Bb * Cc * HW / 4) / 256, 256, 0, stream>>>((const float4*)xs, (const float4*)pvd,
                                                          (float4*)d_out);
}

// Round 3
// 578.854 us; speedup vs baseline: 7.6020x; 2.0447x over previous
//
#include <hip/hip_runtime.h>
#include <hip/hip_bf16.h>

typedef unsigned short ushort_t;
typedef __attribute__((ext_vector_type(8))) short short8;
typedef __attribute__((ext_vector_type(4))) short short4v;
typedef __attribute__((ext_vector_type(4))) float f32x4;

// Problem constants
constexpr int Hh = 256, Ww = 256, HW = Hh * Ww;
constexpr int Bb = 2, Cc = 64, Pp = 3, NOo = 16, FEXc = 48, Nn = 32768;
constexpr int TW = 32, TH = 8;       // spatial tile per block
constexpr int PADC = 72;             // LDS pixel stride (bf16 ch) -> 144B: 16B-aligned, banks spread (<=2-way)
constexpr int HALO = 340;            // 34 x 10 halo pixels

__device__ inline ushort_t f2bf(float v) {
    __hip_bfloat16 h = __float2bfloat16(v);
    return *(ushort_t*)&h;
}
__device__ inline float bf2f(ushort_t u) {
    __hip_bfloat16 h = *(__hip_bfloat16*)&u;
    return __bfloat162float(h);
}

// ---------------- mask weight: wm = mask / max(avg3x3(mask), 1e-8) ----------------
__global__ __launch_bounds__(256) void k_wm(const float* __restrict__ mask,
                                            float* __restrict__ wm) {
    int pos = blockIdx.x * 256 + threadIdx.x;
    int h = pos >> 8, w = pos & 255;
    float s = 0.f;
    #pragma unroll
    for (int dy = -1; dy <= 1; ++dy)
        #pragma unroll
        for (int dx = -1; dx <= 1; ++dx) {
            int hh = h + dy, ww = w + dx;
            if (hh >= 0 && hh < Hh && ww >= 0 && ww < Ww) s += mask[hh * Ww + ww];
        }
    float avg = s * (1.f / 9.f);
    wm[pos] = mask[pos] / fmaxf(avg, 1e-8f);
}

// ---------------- zero a float4 buffer ----------------
__global__ __launch_bounds__(256) void k_zero(float4* __restrict__ p) {
    p[blockIdx.x * 256 + threadIdx.x] = make_float4(0.f, 0.f, 0.f, 0.f);
}

// ---------------- weight transforms: fp32 [oc][cin][3][3] -> bf16 [tap][oc][c64] ----
__global__ __launch_bounds__(256) void k_wx_res(const float* __restrict__ src,
                                                ushort_t* __restrict__ dst) {
    int idx = blockIdx.x * 256 + threadIdx.x;          // < 12*9*64*64 = 442368
    int j = idx / 36864; int rem = idx - j * 36864;
    int t = rem >> 12; int o = (rem >> 6) & 63; int c = rem & 63;
    dst[idx] = f2bf(src[j * 36864 + o * 576 + c * 9 + t]);
}
__global__ __launch_bounds__(256) void k_wx_out(const float* __restrict__ src,
                                                ushort_t* __restrict__ dst) {
    int idx = blockIdx.x * 256 + threadIdx.x;          // < 3*9*16*64 = 27648
    int i = idx / 9216; int rem = idx - i * 9216;
    int t = rem >> 10; int o = (rem >> 6) & 15; int c = rem & 63;
    dst[idx] = f2bf(src[i * 9216 + o * 576 + c * 9 + t]);
}
__global__ __launch_bounds__(256) void k_wx_trunk(const float* __restrict__ src,
                                                  ushort_t* __restrict__ dst) {
    int idx = blockIdx.x * 256 + threadIdx.x;          // < 4*9*48*64 = 110592
    int j = idx / 27648; int rem = idx - j * 27648;
    int t = rem / 3072; int rem2 = rem - t * 3072;
    int o = rem2 >> 6; int c = rem2 & 63;
    float v = (c < 48) ? src[j * (48 * 48 * 9) + o * 432 + c * 9 + t] : 0.f;
    dst[idx] = f2bf(v);
}

// ---------------- xs slice: NCHW fp32 -> masked NHWC bf16 (tiled transpose) ----------
__global__ __launch_bounds__(256) void k_xm(const float* __restrict__ xs_i,
                                            const float* __restrict__ mask,
                                            ushort_t* __restrict__ Xm) {
    __shared__ float l[64 * 65];
    const int p0 = blockIdx.x * 64;
    const int b = blockIdx.y;
    const int tid = threadIdx.x;
    const int px = tid & 63;
    const float mv = mask[p0 + px];
    #pragma unroll
    for (int k = 0; k < 16; ++k) {
        int c = (tid >> 6) + 4 * k;
        l[c * 65 + px] = xs_i[(size_t)(b * 64 + c) * HW + p0 + px] * mv;
    }
    __syncthreads();
    #pragma unroll
    for (int k = 0; k < 2; ++k) {
        int idx = tid + k * 256;
        int p = idx >> 3, c8 = idx & 7;
        short8 v;
        #pragma unroll
        for (int i = 0; i < 8; ++i) v[i] = (short)f2bf(l[(c8 * 8 + i) * 65 + p]);
        *(short8*)&Xm[((size_t)(b * HW) + p0 + p) * 64 + c8 * 8] = v;
    }
}

// ---------------- MFMA implicit-GEMM 3x3 conv (NHWC bf16, ch stride 64) ------------
// MODE 0: out = relu(conv*wm)    MODE 1: out = base + conv*wm    MODE 2: out = conv*wm
template <int OC, int MODE>
__global__ __launch_bounds__(256) void k_mconv(
    const ushort_t* __restrict__ in,       // (B, HW, 64) bf16
    const ushort_t* __restrict__ wB,       // [9][OC][64] bf16
    const float* __restrict__ wm,
    const ushort_t* __restrict__ base,     // (B, HW, 64) bf16 [MODE 1] (may alias out)
    ushort_t* __restrict__ out,            // (B, HW, 64) bf16
    int outCbase) {
    constexpr int NM = OC / 16;
    __shared__ __align__(16) ushort_t lds[HALO * PADC];
    const int tid = threadIdx.x;
    const int w0 = blockIdx.x * TW, h0 = blockIdx.y * TH;
    const int b = blockIdx.z;

    // ---- stage 34x10 halo, 64 ch/pixel, coalesced short8 loads ----
    #pragma unroll
    for (int k = 0; k < 11; ++k) {
        int idx = tid + k * 256;
        if (idx < HALO * 8) {
            int pp = idx >> 3, c8 = idx & 7;
            int r = (pp * 241) >> 13;              // pp/34 for pp<340
            int col = pp - r * 34;
            int gh = h0 + r - 1, gw = w0 + col - 1;
            short8 v = {0, 0, 0, 0, 0, 0, 0, 0};
            if (gh >= 0 && gh < Hh && gw >= 0 && gw < Ww)
                v = *(const short8*)&in[((size_t)(b * HW) + gh * Ww + gw) * 64 + c8 * 8];
            *(short8*)&lds[pp * PADC + c8 * 8] = v;
        }
    }
    __syncthreads();

    const int wv = tid >> 6;                  // wave 0..3 -> rows 2wv, 2wv+1
    const int l = tid & 63;
    const int lo = l & 15, g8 = (l >> 4) * 8;

    f32x4 acc[NM][4];
    #pragma unroll
    for (int mf = 0; mf < NM; ++mf)
        #pragma unroll
        for (int nf = 0; nf < 4; ++nf) acc[mf][nf] = (f32x4){0.f, 0.f, 0.f, 0.f};

    #pragma unroll
    for (int dy = 0; dy < 3; ++dy)
        #pragma unroll
        for (int dx = 0; dx < 3; ++dx)
            #pragma unroll
            for (int ck = 0; ck < 2; ++ck) {
                const int t = dy * 3 + dx;
                short8 bfr[4];
                #pragma unroll
                for (int nf = 0; nf < 4; ++nf) {
                    int hr = 2 * wv + (nf >> 1) + dy;
                    int hc = (nf & 1) * 16 + lo + dx;
                    bfr[nf] = *(const short8*)&lds[(hr * 34 + hc) * PADC + ck * 32 + g8];
                }
                short8 afr[NM];
                #pragma unroll
                for (int mf = 0; mf < NM; ++mf)
                    afr[mf] = *(const short8*)&wB[((t * OC + mf * 16 + lo) * 64) + ck * 32 + g8];
                #pragma unroll
                for (int mf = 0; mf < NM; ++mf)
                    #pragma unroll
                    for (int nf = 0; nf < 4; ++nf)
                        acc[mf][nf] = __builtin_amdgcn_mfma_f32_16x16x32_bf16(
                            afr[mf], bfr[nf], acc[mf][nf], 0, 0, 0);
            }

    // ---- epilogue: col=lane&15 (pixel), row=(lane>>4)*4+j (outch); NHWC 8B stores ----
    #pragma unroll
    for (int nf = 0; nf < 4; ++nf) {
        int r = h0 + 2 * wv + (nf >> 1);
        int x = w0 + (nf & 1) * 16 + lo;
        int pos = r * Ww + x;
        float wmv = wm[pos];
        #pragma unroll
        for (int mf = 0; mf < NM; ++mf) {
            int o0 = outCbase + mf * 16 + (l >> 4) * 4;
            size_t oi = ((size_t)(b * HW) + pos) * 64 + o0;
            float v[4];
            #pragma unroll
            for (int j = 0; j < 4; ++j) v[j] = acc[mf][nf][j] * wmv;
            if (MODE == 0) {
                #pragma unroll
                for (int j = 0; j < 4; ++j) v[j] = fmaxf(v[j], 0.f);
            } else if (MODE == 1) {
                short4v bv = *(const short4v*)&base[oi];
                #pragma unroll
                for (int j = 0; j < 4; ++j) v[j] += bf2f((ushort_t)bv[j]);
            }
            short4v sv;
            #pragma unroll
            for (int j = 0; j < 4; ++j) sv[j] = (short)f2bf(v[j]);
            *(short4v*)&out[oi] = sv;
        }
    }
}

// ---------------- gather f=F+G at yi (NHWC), dsda, MLP 49->48->48->3, scatter ------
__global__ __launch_bounds__(256) void k_gather_mlp(
    const ushort_t* __restrict__ F, const ushort_t* __restrict__ G,
    const int* __restrict__ yi, const float* __restrict__ m,
    const float* __restrict__ w1, const float* __restrict__ b1,
    const float* __restrict__ w2, const float* __restrict__ b2,
    const float* __restrict__ w3, const float* __restrict__ b3,
    float* __restrict__ pvd) {
    int t = blockIdx.x * 256 + threadIdx.x;   // over B*N
    int b = t >> 15;
    int n = t & (Nn - 1);
    int pos = yi[n];

    float h[FEXc + 1];
    {
        const short8* fp = (const short8*)&F[((size_t)(b * HW) + pos) * 64];
        const short8* gp = (const short8*)&G[((size_t)(b * HW) + pos) * 64];
        #pragma unroll
        for (int k = 0; k < 6; ++k) {
            short8 fa = fp[k], ga = gp[k];
            #pragma unroll
            for (int i = 0; i < 8; ++i)
                h[k * 8 + i] = bf2f((ushort_t)fa[i]) + bf2f((ushort_t)ga[i]);
        }
    }
    {
        float det = m[0] * (m[4] * m[8] - m[5] * m[7])
                  - m[1] * (m[3] * m[8] - m[5] * m[6])
                  + m[2] * (m[3] * m[7] - m[4] * m[6]);
        int yr = pos >> 8, xc = pos & 255;
        float wc = m[6] * (float)xc + m[7] * (float)yr + m[8];
        float cw = fmaxf(fabsf(wc), 1e-8f);
        float dsda = fabsf(det) / (cw * cw * cw);
        h[FEXc] = logf(dsda + 1e-8f);
    }

    float h1[FEXc];
    #pragma unroll
    for (int o = 0; o < FEXc; ++o) {
        float a = b1[o];
        #pragma unroll
        for (int c = 0; c < FEXc + 1; ++c) a += w1[o * (FEXc + 1) + c] * h[c];
        h1[o] = fmaxf(a, 0.f);
    }
    float h2[FEXc];
    #pragma unroll
    for (int o = 0; o < FEXc; ++o) {
        float a = b2[o];
        #pragma unroll
        for (int c = 0; c < FEXc; ++c) a += w2[o * FEXc + c] * h1[c];
        h2[o] = fmaxf(a, 0.f);
    }
    #pragma unroll
    for (int p = 0; p < Pp; ++p) {
        float a = b3[p];
        #pragma unroll
        for (int c = 0; c < FEXc; ++c) a += w3[p * FEXc + c] * h2[c];
        pvd[(size_t)(b * Pp + p) * HW + pos] = a;
    }
}

// ---------------- out[b,c,pos] = sum_p pvd[b,p,pos] * xs[p,b,c,pos] ----------------
__global__ __launch_bounds__(256) void k_blend(const float4* __restrict__ xs,
                                               const float4* __restrict__ pvd,
                                               float4* __restrict__ out) {
    int i = blockIdx.x * 256 + threadIdx.x;   // over B*C*HW/4
    int pos4 = i & (HW / 4 - 1);
    int bc = i >> 14;
    int b = bc >> 6;
    float4 acc = make_float4(0.f, 0.f, 0.f, 0.f);
    #pragma unroll
    for (int p = 0; p < Pp; ++p) {
        float4 pv = pvd[(b * Pp + p) * (HW / 4) + pos4];
        float4 x = xs[p * (Bb * Cc * HW / 4) + i];
        acc.x += pv.x * x.x;
        acc.y += pv.y * x.y;
        acc.z += pv.z * x.z;
        acc.w += pv.w * x.w;
    }
    out[i] = acc;
}

extern "C" void kernel_launch(void* const* d_in, const int* in_sizes, int n_in,
                              void* d_out, int out_size, void* d_ws, size_t ws_size,
                              hipStream_t stream) {
    const float* xs        = (const float*)d_in[0];
    const float* mask      = (const float*)d_in[1];
    const int*   yi        = (const int*)d_in[2];
    const float* m         = (const float*)d_in[3];
    const float* ss_res_w  = (const float*)d_in[4];
    const float* ss_out_w  = (const float*)d_in[5];
    const float* feat_res_w= (const float*)d_in[6];
    const float* w1 = (const float*)d_in[7];
    const float* b1 = (const float*)d_in[8];
    const float* w2 = (const float*)d_in[9];
    const float* b2 = (const float*)d_in[10];
    const float* w3 = (const float*)d_in[11];
    const float* b3 = (const float*)d_in[12];

    // workspace: wm f32 | pvd f32 | wB bf16 | A | F | G   (all NHWC bf16, ch-stride 64)
    float* wm  = (float*)d_ws;
    float* pvd = wm + HW;
    ushort_t* wB = (ushort_t*)(pvd + (size_t)Bb * Pp * HW);
    constexpr size_t RES_T = 12 * 9 * 64 * 64;     // 442368
    constexpr size_t OUT_T = 3 * 9 * 16 * 64;      // 27648
    constexpr size_t TRK_T = 4 * 9 * 48 * 64;      // 110592
    ushort_t* A = wB + RES_T + OUT_T + TRK_T;
    ushort_t* F = A + (size_t)Bb * HW * 64;
    ushort_t* G = F + (size_t)Bb * HW * 64;        // reused as Xm during pyramid phase
    ushort_t* Bf = (ushort_t*)d_out;               // bf16 scratch; rewritten fp32 by k_blend

    k_wm<<<HW / 256, 256, 0, stream>>>(mask, wm);
    k_wx_res  <<<RES_T / 256, 256, 0, stream>>>(ss_res_w, wB);
    k_wx_out  <<<OUT_T / 256, 256, 0, stream>>>(ss_out_w, wB + RES_T);
    k_wx_trunk<<<TRK_T / 256, 256, 0, stream>>>(feat_res_w, wB + RES_T + OUT_T);

    const dim3 grid(Ww / TW, Hh / TH, Bb);         // (8, 32, 2)
    const dim3 gxm(HW / 64, Bb);
    for (int i = 0; i < Pp; ++i) {
        const float* xsi = xs + (size_t)i * Bb * Cc * HW;
        const ushort_t* rw = wB + (size_t)i * 4 * 9 * 64 * 64;
        const ushort_t* ow = wB + RES_T + (size_t)i * 9 * 16 * 64;
        k_xm<<<gxm, 256, 0, stream>>>(xsi, mask, G);
        k_mconv<64, 0><<<grid, 256, 0, stream>>>(G,  rw,             wm, nullptr, Bf, 0);
        k_mconv<64, 1><<<grid, 256, 0, stream>>>(Bf, rw + 1 * 36864, wm, G,       A,  0);
        k_mconv<64, 0><<<grid, 256, 0, stream>>>(A,  rw + 2 * 36864, wm, nullptr, Bf, 0);
        k_mconv<64, 1><<<grid, 256, 0, stream>>>(Bf, rw + 3 * 36864, wm, A,       A,  0);
        k_mconv<16, 2><<<grid, 256, 0, stream>>>(A,  ow,             wm, nullptr, F,  i * NOo);
    }
    const ushort_t* tw = wB + RES_T + OUT_T;
    k_mconv<48, 0><<<grid, 256, 0, stream>>>(F,  tw,             wm, nullptr, Bf, 0);
    k_mconv<48, 1><<<grid, 256, 0, stream>>>(Bf, tw + 1 * 27648, wm, F,       G,  0);
    k_mconv<48, 0><<<grid, 256, 0, stream>>>(G,  tw + 2 * 27648, wm, nullptr, Bf, 0);
    k_mconv<48, 1><<<grid, 256, 0, stream>>>(Bf, tw + 3 * 27648, wm, G,       G,  0);

    k_zero<<<(Bb * Pp * HW / 4) / 256, 256, 0, stream>>>((float4*)pvd);
    k_gather_mlp<<<Bb * Nn / 256, 256, 0, stream>>>(F, G, yi, m, w1, b1, w2, b2, w3, b3, pvd);
    k_blend<<<(Bb * Cc * HW / 4) / 256, 256, 0, stream>>>((const float4*)xs, (const float4*)pvd,
                                                          (float4*)d_out);
}

// Round 4
// 501.879 us; speedup vs baseline: 8.7679x; 1.1534x over previous
//
#include <hip/hip_runtime.h>
#include <hip/hip_bf16.h>

typedef unsigned short ushort_t;
typedef __attribute__((ext_vector_type(8))) short short8;
typedef __attribute__((ext_vector_type(4))) short short4v;
typedef __attribute__((ext_vector_type(4))) float f32x4;

// Problem constants
constexpr int Hh = 256, Ww = 256, HW = Hh * Ww;
constexpr int Bb = 2, Cc = 64, Pp = 3, NOo = 16, FEXc = 48, Nn = 32768;
constexpr int TW = 32, TH = 8;       // conv spatial tile per block
constexpr int HALO = 340;            // 34 x 10 halo pixels
constexpr int ROWS = 352;            // staged rows (pad to 4 waves * 11 DMA * 8 rows)
constexpr int PADH = 72;             // gather-MLP LDS point stride (bf16)

__device__ inline ushort_t f2bf(float v) {
    __hip_bfloat16 h = __float2bfloat16(v);
    return *(ushort_t*)&h;
}
__device__ inline float bf2f(ushort_t u) {
    __hip_bfloat16 h = *(__hip_bfloat16*)&u;
    return __bfloat162float(h);
}
// async 16B global->LDS DMA: dest = lds base (wave-uniform) + lane*16
__device__ inline void gload_lds16(const ushort_t* g, ushort_t* l) {
    __builtin_amdgcn_global_load_lds(
        (const __attribute__((address_space(1))) unsigned int*)g,
        (__attribute__((address_space(3))) unsigned int*)l, 16, 0, 0);
}

// ---------------- mask weight: wm = mask / max(avg3x3(mask), 1e-8) ----------------
__global__ __launch_bounds__(256) void k_wm(const float* __restrict__ mask,
                                            float* __restrict__ wm) {
    int pos = blockIdx.x * 256 + threadIdx.x;
    int h = pos >> 8, w = pos & 255;
    float s = 0.f;
    #pragma unroll
    for (int dy = -1; dy <= 1; ++dy)
        #pragma unroll
        for (int dx = -1; dx <= 1; ++dx) {
            int hh = h + dy, ww = w + dx;
            if (hh >= 0 && hh < Hh && ww >= 0 && ww < Ww) s += mask[hh * Ww + ww];
        }
    float avg = s * (1.f / 9.f);
    wm[pos] = mask[pos] / fmaxf(avg, 1e-8f);
}

// ---------------- zero a float4 buffer ----------------
__global__ __launch_bounds__(256) void k_zero(float4* __restrict__ p) {
    p[blockIdx.x * 256 + threadIdx.x] = make_float4(0.f, 0.f, 0.f, 0.f);
}

// ---------------- weight transforms: fp32 [oc][cin][3][3] -> bf16 [tap][oc][c64] ----
__global__ __launch_bounds__(256) void k_wx_res(const float* __restrict__ src,
                                                ushort_t* __restrict__ dst) {
    int idx = blockIdx.x * 256 + threadIdx.x;          // < 12*9*64*64 = 442368
    int j = idx / 36864; int rem = idx - j * 36864;
    int t = rem >> 12; int o = (rem >> 6) & 63; int c = rem & 63;
    dst[idx] = f2bf(src[j * 36864 + o * 576 + c * 9 + t]);
}
__global__ __launch_bounds__(256) void k_wx_out(const float* __restrict__ src,
                                                ushort_t* __restrict__ dst) {
    int idx = blockIdx.x * 256 + threadIdx.x;          // < 3*9*16*64 = 27648
    int i = idx / 9216; int rem = idx - i * 9216;
    int t = rem >> 10; int o = (rem >> 6) & 15; int c = rem & 63;
    dst[idx] = f2bf(src[i * 9216 + o * 576 + c * 9 + t]);
}
__global__ __launch_bounds__(256) void k_wx_trunk(const float* __restrict__ src,
                                                  ushort_t* __restrict__ dst) {
    int idx = blockIdx.x * 256 + threadIdx.x;          // < 4*9*48*64 = 110592
    int j = idx / 27648; int rem = idx - j * 27648;
    int t = rem / 3072; int rem2 = rem - t * 3072;
    int o = rem2 >> 6; int c = rem2 & 63;
    float v = (c < 48) ? src[j * (48 * 48 * 9) + o * 432 + c * 9 + t] : 0.f;
    dst[idx] = f2bf(v);
}
// MLP weights -> A-frag layout [out][k64] bf16, biases folded at k=49 (L1) / 48 (L2) / 49 (L3)
__global__ __launch_bounds__(256) void k_wx_mlp(
    const float* __restrict__ w1, const float* __restrict__ b1,
    const float* __restrict__ w2, const float* __restrict__ b2,
    const float* __restrict__ w3, const float* __restrict__ b3,
    ushort_t* __restrict__ dst) {
    int idx = blockIdx.x * 256 + threadIdx.x;          // < 7168
    float v = 0.f;
    if (idx < 3072) {                                  // wA1 [48][64]
        int o = idx >> 6, c = idx & 63;
        v = (c < 49) ? w1[o * 49 + c] : (c == 49 ? b1[o] : 0.f);
    } else if (idx < 6144) {                           // wA2 [48][64]
        int o = (idx - 3072) >> 6, c = idx & 63;
        v = (c < 48) ? w2[o * 48 + c] : (c == 48 ? b2[o] : 0.f);
    } else {                                           // wA3 [16][64]
        int o = (idx - 6144) >> 6, c = idx & 63;
        if (o < 3) v = (c < 48) ? w3[o * 48 + c] : (c == 49 ? b3[o] : 0.f);
    }
    dst[idx] = f2bf(v);
}

// ---------------- xs slice: NCHW fp32 -> masked NHWC bf16 (tiled transpose) ----------
__global__ __launch_bounds__(256) void k_xm(const float* __restrict__ xs_i,
                                            const float* __restrict__ mask,
                                            ushort_t* __restrict__ Xm) {
    __shared__ float l[64 * 65];
    const int p0 = blockIdx.x * 64;
    const int b = blockIdx.y;
    const int tid = threadIdx.x;
    const int px = tid & 63;
    const float mv = mask[p0 + px];
    #pragma unroll
    for (int k = 0; k < 16; ++k) {
        int c = (tid >> 6) + 4 * k;
        l[c * 65 + px] = xs_i[(size_t)(b * 64 + c) * HW + p0 + px] * mv;
    }
    __syncthreads();
    #pragma unroll
    for (int k = 0; k < 2; ++k) {
        int idx = tid + k * 256;
        int p = idx >> 3, c8 = idx & 7;
        short8 v;
        #pragma unroll
        for (int i = 0; i < 8; ++i) v[i] = (short)f2bf(l[(c8 * 8 + i) * 65 + p]);
        *(short8*)&Xm[((size_t)(b * HW) + p0 + p) * 64 + c8 * 8] = v;
    }
}

// ---------------- MFMA implicit-GEMM 3x3 conv (NHWC bf16, ch stride 64) ------------
// Staging: global_load_lds width16, linear LDS [row][64ch], XOR slot-swizzle (slot^=(row&7))
// applied via pre-swizzled per-lane GLOBAL source; reads un-swizzle with the same XOR.
// MODE 0: out = relu(conv*wm)    MODE 1: out = base + conv*wm    MODE 2: out = conv*wm
template <int OC, int MODE>
__global__ __launch_bounds__(256) void k_mconv(
    const ushort_t* __restrict__ in,       // (B, HW, 64) bf16
    const ushort_t* __restrict__ wB,       // [9][OC][64] bf16
    const float* __restrict__ wm,
    const ushort_t* __restrict__ base,     // (B, HW, 64) bf16 [MODE 1] (may alias out)
    ushort_t* __restrict__ out,            // (B, HW, 64) bf16
    int outCbase) {
    constexpr int NM = OC / 16;
    __shared__ __align__(1024) ushort_t lds[ROWS * 64];
    const int tid = threadIdx.x;
    const int wv = tid >> 6;
    const int ln = tid & 63;
    const int w0 = blockIdx.x * TW, h0 = blockIdx.y * TH;
    const int b = blockIdx.z;
    const ushort_t* inb = in + (size_t)b * HW * 64;

    // ---- stage: 11 DMA instructions per wave (8 rows x 128B each) ----
    #pragma unroll
    for (int k = 0; k < 11; ++k) {
        int pp = wv * 88 + k * 8 + (ln >> 3);
        int r = (pp * 241) >> 13;                  // pp/34 for pp<352
        int col = pp - r * 34;
        int gh = h0 + r - 1, gw = w0 + col - 1;
        int ghc = min(max(gh, 0), 255), gwc = min(max(gw, 0), 255);
        int slot = (ln & 7) ^ (pp & 7);
        gload_lds16(inb + ((size_t)(ghc * Ww + gwc)) * 64 + slot * 8,
                    &lds[(wv * 88 + k * 8) * 64]);
    }
    asm volatile("s_waitcnt vmcnt(0)" ::: "memory");
    // ---- zero-fix OOB halo rows (edge blocks only), per-wave-owned rows ----
    if (blockIdx.x == 0 || blockIdx.x == (Ww / TW - 1) ||
        blockIdx.y == 0 || blockIdx.y == (Hh / TH - 1)) {
        const short8 z = {0, 0, 0, 0, 0, 0, 0, 0};
        for (int q = ln; q < 88; q += 64) {
            int pp = wv * 88 + q;
            if (pp < HALO) {
                int r = (pp * 241) >> 13;
                int col = pp - r * 34;
                int gh = h0 + r - 1, gw = w0 + col - 1;
                if (gh < 0 || gh > 255 || gw < 0 || gw > 255) {
                    #pragma unroll
                    for (int s = 0; s < 8; ++s) *(short8*)&lds[pp * 64 + s * 8] = z;
                }
            }
        }
    }
    __syncthreads();

    const int lo = ln & 15, g8 = (ln >> 4) * 8;

    f32x4 acc[NM][4];
    #pragma unroll
    for (int mf = 0; mf < NM; ++mf)
        #pragma unroll
        for (int nf = 0; nf < 4; ++nf) acc[mf][nf] = (f32x4){0.f, 0.f, 0.f, 0.f};

    #pragma unroll
    for (int dy = 0; dy < 3; ++dy)
        #pragma unroll
        for (int dx = 0; dx < 3; ++dx)
            #pragma unroll
            for (int ck = 0; ck < 2; ++ck) {
                const int t = dy * 3 + dx;
                const int sl = ck * 4 + (ln >> 4);
                short8 bfr[4];
                #pragma unroll
                for (int nf = 0; nf < 4; ++nf) {
                    int pp2 = (2 * wv + (nf >> 1) + dy) * 34 + (nf & 1) * 16 + lo + dx;
                    bfr[nf] = *(const short8*)&lds[pp2 * 64 + ((sl ^ (pp2 & 7)) << 3)];
                }
                short8 afr[NM];
                #pragma unroll
                for (int mf = 0; mf < NM; ++mf)
                    afr[mf] = *(const short8*)&wB[((t * OC + mf * 16 + lo) * 64) + ck * 32 + g8];
                #pragma unroll
                for (int mf = 0; mf < NM; ++mf)
                    #pragma unroll
                    for (int nf = 0; nf < 4; ++nf)
                        acc[mf][nf] = __builtin_amdgcn_mfma_f32_16x16x32_bf16(
                            afr[mf], bfr[nf], acc[mf][nf], 0, 0, 0);
            }

    // ---- epilogue: C col=lane&15 (pixel), row=(lane>>4)*4+j (outch); NHWC 8B stores ----
    #pragma unroll
    for (int nf = 0; nf < 4; ++nf) {
        int r = h0 + 2 * wv + (nf >> 1);
        int x = w0 + (nf & 1) * 16 + lo;
        int pos = r * Ww + x;
        float wmv = wm[pos];
        #pragma unroll
        for (int mf = 0; mf < NM; ++mf) {
            int o0 = outCbase + mf * 16 + (ln >> 4) * 4;
            size_t oi = ((size_t)(b * HW) + pos) * 64 + o0;
            float v[4];
            #pragma unroll
            for (int j = 0; j < 4; ++j) v[j] = acc[mf][nf][j] * wmv;
            if (MODE == 0) {
                #pragma unroll
                for (int j = 0; j < 4; ++j) v[j] = fmaxf(v[j], 0.f);
            } else if (MODE == 1) {
                short4v bv = *(const short4v*)&base[oi];
                #pragma unroll
                for (int j = 0; j < 4; ++j) v[j] += bf2f((ushort_t)bv[j]);
            }
            short4v sv;
            #pragma unroll
            for (int j = 0; j < 4; ++j) sv[j] = (short)f2bf(v[j]);
            *(short4v*)&out[oi] = sv;
        }
    }
}

// ---------------- gather + MLP via MFMA: 64 pts/block, 16 pts/wave --------------------
// h layout per wave in LDS: [16 pts][PADH=72] bf16. ch0..47 = F+G, 48 = dsda (L1) /
// 1.0 (L2 bias), 49 = 1.0 (L1/L3 bias), 50..63 = 0. Layers ping-pong hA <-> hB.
__global__ __launch_bounds__(256) void k_gather_mlp(
    const ushort_t* __restrict__ F, const ushort_t* __restrict__ G,
    const int* __restrict__ yi, const float* __restrict__ m,
    const ushort_t* __restrict__ wA1, const ushort_t* __restrict__ wA2,
    const ushort_t* __restrict__ wA3, float* __restrict__ pvd) {
    __shared__ __align__(16) ushort_t HA[4 * 16 * PADH];
    __shared__ __align__(16) ushort_t HB[4 * 16 * PADH];
    const int tid = threadIdx.x, wv = tid >> 6, ln = tid & 63;
    ushort_t* ha = HA + wv * 16 * PADH;
    ushort_t* hb = HB + wv * 16 * PADH;
    const int t0 = blockIdx.x * 64 + wv * 16;     // first point of this wave
    const int b = t0 >> 15;                        // wave-uniform batch
    const int lo = ln & 15, g8 = (ln >> 4) * 8;

    // ---- phase 1: gather F+G (96 slot-jobs), dsda + bias/zero fills ----
    #pragma unroll
    for (int rnd = 0; rnd < 2; ++rnd) {
        int j = rnd * 64 + ln;
        if (j < 96) {
            int pt = j / 6, sl = j - pt * 6;
            int n = (t0 + pt) & (Nn - 1);
            int pos = yi[n];
            size_t gi = ((size_t)(b * HW) + pos) * 64 + sl * 8;
            short8 fa = *(const short8*)&F[gi];
            short8 ga = *(const short8*)&G[gi];
            short8 sv;
            #pragma unroll
            for (int i = 0; i < 8; ++i)
                sv[i] = (short)f2bf(bf2f((ushort_t)fa[i]) + bf2f((ushort_t)ga[i]));
            *(short8*)&ha[pt * PADH + sl * 8] = sv;
        }
    }
    if (ln < 16) {
        int pt = ln;
        int n = (t0 + pt) & (Nn - 1);
        int pos = yi[n];
        float det = m[0] * (m[4] * m[8] - m[5] * m[7])
                  - m[1] * (m[3] * m[8] - m[5] * m[6])
                  + m[2] * (m[3] * m[7] - m[4] * m[6]);
        int yr = pos >> 8, xc = pos & 255;
        float wc = m[6] * (float)xc + m[7] * (float)yr + m[8];
        float cw = fmaxf(fabsf(wc), 1e-8f);
        float dsda = fabsf(det) / (cw * cw * cw);
        float ld = logf(dsda + 1e-8f);
        const ushort_t one = f2bf(1.0f);
        short8 z = {0, 0, 0, 0, 0, 0, 0, 0};
        short8 sa = z; sa[0] = (short)f2bf(ld); sa[1] = (short)one;   // ha: dsda, 1.0
        short8 sb = z; sb[0] = (short)one;                            // hb: 1.0 (L2 bias)
        *(short8*)&ha[pt * PADH + 48] = sa;
        *(short8*)&ha[pt * PADH + 56] = z;
        *(short8*)&hb[pt * PADH + 48] = sb;
        *(short8*)&hb[pt * PADH + 56] = z;
    }
    asm volatile("s_waitcnt lgkmcnt(0)" ::: "memory");

    // ---- layer 1: h(49+1) -> 48, relu ----
    f32x4 a1[3] = {{0.f,0.f,0.f,0.f},{0.f,0.f,0.f,0.f},{0.f,0.f,0.f,0.f}};
    #pragma unroll
    for (int ks = 0; ks < 2; ++ks) {
        short8 bf = *(const short8*)&ha[lo * PADH + ks * 32 + g8];
        #pragma unroll
        for (int mf = 0; mf < 3; ++mf) {
            short8 af = *(const short8*)&wA1[(mf * 16 + lo) * 64 + ks * 32 + g8];
            a1[mf] = __builtin_amdgcn_mfma_f32_16x16x32_bf16(af, bf, a1[mf], 0, 0, 0);
        }
    }
    #pragma unroll
    for (int mf = 0; mf < 3; ++mf) {
        short4v sv;
        #pragma unroll
        for (int j = 0; j < 4; ++j) sv[j] = (short)f2bf(fmaxf(a1[mf][j], 0.f));
        *(short4v*)&hb[lo * PADH + mf * 16 + (ln >> 4) * 4] = sv;
    }
    asm volatile("s_waitcnt lgkmcnt(0)" ::: "memory");

    // ---- layer 2: 48 -> 48, relu ----
    f32x4 a2[3] = {{0.f,0.f,0.f,0.f},{0.f,0.f,0.f,0.f},{0.f,0.f,0.f,0.f}};
    #pragma unroll
    for (int ks = 0; ks < 2; ++ks) {
        short8 bf = *(const short8*)&hb[lo * PADH + ks * 32 + g8];
        #pragma unroll
        for (int mf = 0; mf < 3; ++mf) {
            short8 af = *(const short8*)&wA2[(mf * 16 + lo) * 64 + ks * 32 + g8];
            a2[mf] = __builtin_amdgcn_mfma_f32_16x16x32_bf16(af, bf, a2[mf], 0, 0, 0);
        }
    }
    #pragma unroll
    for (int mf = 0; mf < 3; ++mf) {
        short4v sv;
        #pragma unroll
        for (int j = 0; j < 4; ++j) sv[j] = (short)f2bf(fmaxf(a2[mf][j], 0.f));
        *(short4v*)&ha[lo * PADH + mf * 16 + (ln >> 4) * 4] = sv;
    }
    asm volatile("s_waitcnt lgkmcnt(0)" ::: "memory");

    // ---- layer 3: 48 -> 3 (rows 0..2 of 16), scatter to pvd ----
    f32x4 a3 = {0.f, 0.f, 0.f, 0.f};
    #pragma unroll
    for (int ks = 0; ks < 2; ++ks) {
        short8 bf = *(const short8*)&ha[lo * PADH + ks * 32 + g8];
        short8 af = *(const short8*)&wA3[lo * 64 + ks * 32 + g8];
        a3 = __builtin_amdgcn_mfma_f32_16x16x32_bf16(af, bf, a3, 0, 0, 0);
    }
    if (ln < 16) {                                   // rows 0..3 live in lanes 0..15
        int n = (t0 + lo) & (Nn - 1);
        int pos = yi[n];
        #pragma unroll
        for (int j = 0; j < 3; ++j)
            pvd[(size_t)(b * Pp + j) * HW + pos] = a3[j];
    }
}

// ---------------- out[b,c,pos] = sum_p pvd[b,p,pos] * xs[p,b,c,pos] ----------------
__global__ __launch_bounds__(256) void k_blend(const float4* __restrict__ xs,
                                               const float4* __restrict__ pvd,
                                               float4* __restrict__ out) {
    int i = blockIdx.x * 256 + threadIdx.x;   // over B*C*HW/4
    int pos4 = i & (HW / 4 - 1);
    int bc = i >> 14;
    int b = bc >> 6;
    float4 acc = make_float4(0.f, 0.f, 0.f, 0.f);
    #pragma unroll
    for (int p = 0; p < Pp; ++p) {
        float4 pv = pvd[(b * Pp + p) * (HW / 4) + pos4];
        float4 x = xs[p * (Bb * Cc * HW / 4) + i];
        acc.x += pv.x * x.x;
        acc.y += pv.y * x.y;
        acc.z += pv.z * x.z;
        acc.w += pv.w * x.w;
    }
    out[i] = acc;
}

extern "C" void kernel_launch(void* const* d_in, const int* in_sizes, int n_in,
                              void* d_out, int out_size, void* d_ws, size_t ws_size,
                              hipStream_t stream) {
    const float* xs        = (const float*)d_in[0];
    const float* mask      = (const float*)d_in[1];
    const int*   yi        = (const int*)d_in[2];
    const float* m         = (const float*)d_in[3];
    const float* ss_res_w  = (const float*)d_in[4];
    const float* ss_out_w  = (const float*)d_in[5];
    const float* feat_res_w= (const float*)d_in[6];
    const float* w1 = (const float*)d_in[7];
    const float* b1 = (const float*)d_in[8];
    const float* w2 = (const float*)d_in[9];
    const float* b2 = (const float*)d_in[10];
    const float* w3 = (const float*)d_in[11];
    const float* b3 = (const float*)d_in[12];

    // workspace: wm f32 | pvd f32 | wB bf16 | wA bf16 | A | F | G  (NHWC bf16, stride 64)
    float* wm  = (float*)d_ws;
    float* pvd = wm + HW;
    ushort_t* wB = (ushort_t*)(pvd + (size_t)Bb * Pp * HW);
    constexpr size_t RES_T = 12 * 9 * 64 * 64;     // 442368
    constexpr size_t OUT_T = 3 * 9 * 16 * 64;      // 27648
    constexpr size_t TRK_T = 4 * 9 * 48 * 64;      // 110592
    constexpr size_t MLP_T = 7168;
    ushort_t* wA = wB + RES_T + OUT_T + TRK_T;
    ushort_t* A = wA + MLP_T;
    ushort_t* F = A + (size_t)Bb * HW * 64;
    ushort_t* G = F + (size_t)Bb * HW * 64;        // reused as Xm during pyramid phase
    ushort_t* Bf = (ushort_t*)d_out;               // bf16 scratch for 64ch pyramid pingpong only

    k_wm<<<HW / 256, 256, 0, stream>>>(mask, wm);
    k_wx_res  <<<RES_T / 256, 256, 0, stream>>>(ss_res_w, wB);
    k_wx_out  <<<OUT_T / 256, 256, 0, stream>>>(ss_out_w, wB + RES_T);
    k_wx_trunk<<<TRK_T / 256, 256, 0, stream>>>(feat_res_w, wB + RES_T + OUT_T);
    k_wx_mlp  <<<MLP_T / 256, 256, 0, stream>>>(w1, b1, w2, b2, w3, b3, wA);

    const dim3 grid(Ww / TW, Hh / TH, Bb);         // (8, 32, 2)
    const dim3 gxm(HW / 64, Bb);
    for (int i = 0; i < Pp; ++i) {
        const float* xsi = xs + (size_t)i * Bb * Cc * HW;
        const ushort_t* rw = wB + (size_t)i * 4 * 9 * 64 * 64;
        const ushort_t* ow = wB + RES_T + (size_t)i * 9 * 16 * 64;
        k_xm<<<gxm, 256, 0, stream>>>(xsi, mask, G);
        k_mconv<64, 0><<<grid, 256, 0, stream>>>(G,  rw,             wm, nullptr, Bf, 0);
        k_mconv<64, 1><<<grid, 256, 0, stream>>>(Bf, rw + 1 * 36864, wm, G,       A,  0);
        k_mconv<64, 0><<<grid, 256, 0, stream>>>(A,  rw + 2 * 36864, wm, nullptr, Bf, 0);
        k_mconv<64, 1><<<grid, 256, 0, stream>>>(Bf, rw + 3 * 36864, wm, A,       A,  0);
        k_mconv<16, 2><<<grid, 256, 0, stream>>>(A,  ow,             wm, nullptr, F,  i * NOo);
    }
    // trunk ping-pongs through A (finite stale bf16 in ch48..63; never through d_out)
    const ushort_t* tw = wB + RES_T + OUT_T;
    k_mconv<48, 0><<<grid, 256, 0, stream>>>(F,  tw,             wm, nullptr, A, 0);
    k_mconv<48, 1><<<grid, 256, 0, stream>>>(A,  tw + 1 * 27648, wm, F,       G, 0);
    k_mconv<48, 0><<<grid, 256, 0, stream>>>(G,  tw + 2 * 27648, wm, nullptr, A, 0);
    k_mconv<48, 1><<<grid, 256, 0, stream>>>(A,  tw + 3 * 27648, wm, G,       G, 0);

    k_zero<<<(Bb * Pp * HW / 4) / 256, 256, 0, stream>>>((float4*)pvd);
    k_gather_mlp<<<Bb * Nn / 64, 256, 0, stream>>>(F, G, yi, m,
        wA, wA + 3072, wA + 6144, pvd);
    k_blend<<<(Bb * Cc * HW / 4) / 256, 256, 0, stream>>>((const float4*)xs, (const float4*)pvd,
                                                          (float4*)d_out);
}

// Round 5
// 484.079 us; speedup vs baseline: 9.0903x; 1.0368x over previous
//
#include <hip/hip_runtime.h>
#include <hip/hip_bf16.h>

typedef unsigned short ushort_t;
typedef __attribute__((ext_vector_type(8))) short short8;
typedef __attribute__((ext_vector_type(4))) short short4v;
typedef __attribute__((ext_vector_type(4))) float f32x4;

// Problem constants
constexpr int Hh = 256, Ww = 256, HW = Hh * Ww;
constexpr int Bb = 2, Cc = 64, Pp = 3, NOo = 16, FEXc = 48, Nn = 32768;
constexpr int TW = 32, TH = 8;       // conv spatial tile per block
constexpr int HALO = 340;            // 34 x 10 halo pixels
constexpr int ROWS = 352;            // staged rows (4 waves * 11 DMA * 8 rows)
constexpr int PADH = 72;             // gather-MLP LDS point stride (bf16)

__device__ inline ushort_t f2bf(float v) {
    __hip_bfloat16 h = __float2bfloat16(v);
    return *(ushort_t*)&h;
}
__device__ inline float bf2f(ushort_t u) {
    __hip_bfloat16 h = *(__hip_bfloat16*)&u;
    return __bfloat162float(h);
}
// async 16B global->LDS DMA: dest = lds base (wave-uniform) + lane*16
__device__ inline void gload_lds16(const ushort_t* g, ushort_t* l) {
    __builtin_amdgcn_global_load_lds(
        (const __attribute__((address_space(1))) unsigned int*)g,
        (__attribute__((address_space(3))) unsigned int*)l, 16, 0, 0);
}

// ---------------- mask weight: wm = mask / max(avg3x3(mask), 1e-8) ----------------
__global__ __launch_bounds__(256) void k_wm(const float* __restrict__ mask,
                                            float* __restrict__ wm) {
    int pos = blockIdx.x * 256 + threadIdx.x;
    int h = pos >> 8, w = pos & 255;
    float s = 0.f;
    #pragma unroll
    for (int dy = -1; dy <= 1; ++dy)
        #pragma unroll
        for (int dx = -1; dx <= 1; ++dx) {
            int hh = h + dy, ww = w + dx;
            if (hh >= 0 && hh < Hh && ww >= 0 && ww < Ww) s += mask[hh * Ww + ww];
        }
    float avg = s * (1.f / 9.f);
    wm[pos] = mask[pos] / fmaxf(avg, 1e-8f);
}

// ---------------- zero a float4 buffer ----------------
__global__ __launch_bounds__(256) void k_zero(float4* __restrict__ p) {
    p[blockIdx.x * 256 + threadIdx.x] = make_float4(0.f, 0.f, 0.f, 0.f);
}

// ---------------- weight transforms: fp32 [oc][cin][3][3] -> bf16 [tap][oc][c64] ----
__global__ __launch_bounds__(256) void k_wx_res(const float* __restrict__ src,
                                                ushort_t* __restrict__ dst) {
    int idx = blockIdx.x * 256 + threadIdx.x;          // < 12*9*64*64 = 442368
    int j = idx / 36864; int rem = idx - j * 36864;
    int t = rem >> 12; int o = (rem >> 6) & 63; int c = rem & 63;
    dst[idx] = f2bf(src[j * 36864 + o * 576 + c * 9 + t]);
}
__global__ __launch_bounds__(256) void k_wx_out(const float* __restrict__ src,
                                                ushort_t* __restrict__ dst) {
    int idx = blockIdx.x * 256 + threadIdx.x;          // < 3*9*16*64 = 27648
    int i = idx / 9216; int rem = idx - i * 9216;
    int t = rem >> 10; int o = (rem >> 6) & 15; int c = rem & 63;
    dst[idx] = f2bf(src[i * 9216 + o * 576 + c * 9 + t]);
}
__global__ __launch_bounds__(256) void k_wx_trunk(const float* __restrict__ src,
                                                  ushort_t* __restrict__ dst) {
    int idx = blockIdx.x * 256 + threadIdx.x;          // < 4*9*48*64 = 110592
    int j = idx / 27648; int rem = idx - j * 27648;
    int t = rem / 3072; int rem2 = rem - t * 3072;
    int o = rem2 >> 6; int c = rem2 & 63;
    float v = (c < 48) ? src[j * (48 * 48 * 9) + o * 432 + c * 9 + t] : 0.f;
    dst[idx] = f2bf(v);
}
// MLP weights -> A-frag layout [out][k64] bf16, biases folded at k=49 (L1) / 48 (L2) / 49 (L3)
__global__ __launch_bounds__(256) void k_wx_mlp(
    const float* __restrict__ w1, const float* __restrict__ b1,
    const float* __restrict__ w2, const float* __restrict__ b2,
    const float* __restrict__ w3, const float* __restrict__ b3,
    ushort_t* __restrict__ dst) {
    int idx = blockIdx.x * 256 + threadIdx.x;          // < 7168
    float v = 0.f;
    if (idx < 3072) {                                  // wA1 [48][64]
        int o = idx >> 6, c = idx & 63;
        v = (c < 49) ? w1[o * 49 + c] : (c == 49 ? b1[o] : 0.f);
    } else if (idx < 6144) {                           // wA2 [48][64]
        int o = (idx - 3072) >> 6, c = idx & 63;
        v = (c < 48) ? w2[o * 48 + c] : (c == 48 ? b2[o] : 0.f);
    } else {                                           // wA3 [16][64]
        int o = (idx - 6144) >> 6, c = idx & 63;
        if (o < 3) v = (c < 48) ? w3[o * 48 + c] : (c == 49 ? b3[o] : 0.f);
    }
    dst[idx] = f2bf(v);
}

// ------- xs: NCHW fp32 -> masked NHWC bf16, all pyramids (z = i*B + b) --------------
__global__ __launch_bounds__(256) void k_xm(const float* __restrict__ xs,
                                            const float* __restrict__ mask,
                                            ushort_t* __restrict__ X) {
    __shared__ float l[64 * 65];
    const int p0 = blockIdx.x * 64;
    const size_t zoff = (size_t)blockIdx.y * 64 * HW;   // (P,B) both: stride 64*HW
    const int tid = threadIdx.x;
    const int px = tid & 63;
    const float mv = mask[p0 + px];
    #pragma unroll
    for (int k = 0; k < 16; ++k) {
        int c = (tid >> 6) + 4 * k;
        l[c * 65 + px] = xs[zoff + (size_t)c * HW + p0 + px] * mv;
    }
    __syncthreads();
    #pragma unroll
    for (int k = 0; k < 2; ++k) {
        int idx = tid + k * 256;
        int p = idx >> 3, c8 = idx & 7;
        short8 v;
        #pragma unroll
        for (int i = 0; i < 8; ++i) v[i] = (short)f2bf(l[(c8 * 8 + i) * 65 + p]);
        *(short8*)&X[zoff + (size_t)(p0 + p) * 64 + c8 * 8] = v;
    }
}

// ---------------- MFMA implicit-GEMM 3x3 conv (NHWC bf16, ch stride 64) ------------
// z = pyramid*2 + batch (or just batch for trunk, wstride=0). in/base/out offset by
// z*HW*64; weights by (z>>1)*wstride. TOF: out goes to F (B,HW,64) at chan (z>>1)*16.
// Staging: global_load_lds w16, linear LDS, XOR slot-swizzle via pre-swizzled source.
// MODE 0: out = relu(conv*wm)    MODE 1: out = base + conv*wm    MODE 2: out = conv*wm
template <int OC, int MODE, bool TOF>
__global__ __launch_bounds__(256) void k_mconv(
    const ushort_t* __restrict__ in,
    const ushort_t* __restrict__ wgt, int wstride,
    const float* __restrict__ wm,
    const ushort_t* __restrict__ base,
    ushort_t* __restrict__ out) {
    constexpr int NM = OC / 16;
    __shared__ __align__(1024) ushort_t lds[ROWS * 64];
    const int tid = threadIdx.x;
    const int wv = tid >> 6;
    const int ln = tid & 63;
    const int w0 = blockIdx.x * TW, h0 = blockIdx.y * TH;
    const int zz = blockIdx.z;
    const ushort_t* inb = in + (size_t)zz * HW * 64;
    const ushort_t* wB = wgt + (size_t)(zz >> 1) * wstride;
    const ushort_t* baseb = base ? base + (size_t)zz * HW * 64 : nullptr;
    ushort_t* outb = TOF ? out + (size_t)(zz & 1) * HW * 64 : out + (size_t)zz * HW * 64;
    const int ocb = TOF ? (zz >> 1) * 16 : 0;

    // ---- stage: 11 DMA instructions per wave (8 rows x 128B each) ----
    #pragma unroll
    for (int k = 0; k < 11; ++k) {
        int pp = wv * 88 + k * 8 + (ln >> 3);
        int r = (pp * 241) >> 13;                  // pp/34 for pp<352
        int col = pp - r * 34;
        int gh = h0 + r - 1, gw = w0 + col - 1;
        int ghc = min(max(gh, 0), 255), gwc = min(max(gw, 0), 255);
        int slot = (ln & 7) ^ (pp & 7);
        gload_lds16(inb + ((size_t)(ghc * Ww + gwc)) * 64 + slot * 8,
                    &lds[(wv * 88 + k * 8) * 64]);
    }
    asm volatile("s_waitcnt vmcnt(0)" ::: "memory");
    // ---- zero-fix OOB halo rows (edge blocks only), per-wave-owned rows ----
    if (blockIdx.x == 0 || blockIdx.x == (Ww / TW - 1) ||
        blockIdx.y == 0 || blockIdx.y == (Hh / TH - 1)) {
        const short8 z = {0, 0, 0, 0, 0, 0, 0, 0};
        for (int q = ln; q < 88; q += 64) {
            int pp = wv * 88 + q;
            if (pp < HALO) {
                int r = (pp * 241) >> 13;
                int col = pp - r * 34;
                int gh = h0 + r - 1, gw = w0 + col - 1;
                if (gh < 0 || gh > 255 || gw < 0 || gw > 255) {
                    #pragma unroll
                    for (int s = 0; s < 8; ++s) *(short8*)&lds[pp * 64 + s * 8] = z;
                }
            }
        }
    }
    __syncthreads();

    const int lo = ln & 15, g8 = (ln >> 4) * 8;

    f32x4 acc[NM][4];
    #pragma unroll
    for (int mf = 0; mf < NM; ++mf)
        #pragma unroll
        for (int nf = 0; nf < 4; ++nf) acc[mf][nf] = (f32x4){0.f, 0.f, 0.f, 0.f};

    #pragma unroll
    for (int dy = 0; dy < 3; ++dy)
        #pragma unroll
        for (int dx = 0; dx < 3; ++dx)
            #pragma unroll
            for (int ck = 0; ck < 2; ++ck) {
                const int t = dy * 3 + dx;
                const int sl = ck * 4 + (ln >> 4);
                short8 bfr[4];
                #pragma unroll
                for (int nf = 0; nf < 4; ++nf) {
                    int pp2 = (2 * wv + (nf >> 1) + dy) * 34 + (nf & 1) * 16 + lo + dx;
                    bfr[nf] = *(const short8*)&lds[pp2 * 64 + ((sl ^ (pp2 & 7)) << 3)];
                }
                short8 afr[NM];
                #pragma unroll
                for (int mf = 0; mf < NM; ++mf)
                    afr[mf] = *(const short8*)&wB[((t * OC + mf * 16 + lo) * 64) + ck * 32 + g8];
                #pragma unroll
                for (int mf = 0; mf < NM; ++mf)
                    #pragma unroll
                    for (int nf = 0; nf < 4; ++nf)
                        acc[mf][nf] = __builtin_amdgcn_mfma_f32_16x16x32_bf16(
                            afr[mf], bfr[nf], acc[mf][nf], 0, 0, 0);
            }

    // ---- epilogue: C col=lane&15 (pixel), row=(lane>>4)*4+j (outch); NHWC 8B stores ----
    #pragma unroll
    for (int nf = 0; nf < 4; ++nf) {
        int r = h0 + 2 * wv + (nf >> 1);
        int x = w0 + (nf & 1) * 16 + lo;
        int pos = r * Ww + x;
        float wmv = wm[pos];
        #pragma unroll
        for (int mf = 0; mf < NM; ++mf) {
            int o0 = ocb + mf * 16 + (ln >> 4) * 4;
            size_t oi = (size_t)pos * 64 + o0;
            float v[4];
            #pragma unroll
            for (int j = 0; j < 4; ++j) v[j] = acc[mf][nf][j] * wmv;
            if (MODE == 0) {
                #pragma unroll
                for (int j = 0; j < 4; ++j) v[j] = fmaxf(v[j], 0.f);
            } else if (MODE == 1) {
                short4v bv = *(const short4v*)&baseb[oi];
                #pragma unroll
                for (int j = 0; j < 4; ++j) v[j] += bf2f((ushort_t)bv[j]);
            }
            short4v sv;
            #pragma unroll
            for (int j = 0; j < 4; ++j) sv[j] = (short)f2bf(v[j]);
            *(short4v*)&outb[oi] = sv;
        }
    }
}

// ---------------- gather + MLP via MFMA: 64 pts/block, 16 pts/wave --------------------
__global__ __launch_bounds__(256) void k_gather_mlp(
    const ushort_t* __restrict__ F, const ushort_t* __restrict__ G,
    const int* __restrict__ yi, const float* __restrict__ m,
    const ushort_t* __restrict__ wA1, const ushort_t* __restrict__ wA2,
    const ushort_t* __restrict__ wA3, float* __restrict__ pvd) {
    __shared__ __align__(16) ushort_t HA[4 * 16 * PADH];
    __shared__ __align__(16) ushort_t HB[4 * 16 * PADH];
    const int tid = threadIdx.x, wv = tid >> 6, ln = tid & 63;
    ushort_t* ha = HA + wv * 16 * PADH;
    ushort_t* hb = HB + wv * 16 * PADH;
    const int t0 = blockIdx.x * 64 + wv * 16;
    const int b = t0 >> 15;
    const int lo = ln & 15, g8 = (ln >> 4) * 8;

    #pragma unroll
    for (int rnd = 0; rnd < 2; ++rnd) {
        int j = rnd * 64 + ln;
        if (j < 96) {
            int pt = j / 6, sl = j - pt * 6;
            int n = (t0 + pt) & (Nn - 1);
            int pos = yi[n];
            size_t gi = ((size_t)(b * HW) + pos) * 64 + sl * 8;
            short8 fa = *(const short8*)&F[gi];
            short8 ga = *(const short8*)&G[gi];
            short8 sv;
            #pragma unroll
            for (int i = 0; i < 8; ++i)
                sv[i] = (short)f2bf(bf2f((ushort_t)fa[i]) + bf2f((ushort_t)ga[i]));
            *(short8*)&ha[pt * PADH + sl * 8] = sv;
        }
    }
    if (ln < 16) {
        int pt = ln;
        int n = (t0 + pt) & (Nn - 1);
        int pos = yi[n];
        float det = m[0] * (m[4] * m[8] - m[5] * m[7])
                  - m[1] * (m[3] * m[8] - m[5] * m[6])
                  + m[2] * (m[3] * m[7] - m[4] * m[6]);
        int yr = pos >> 8, xc = pos & 255;
        float wc = m[6] * (float)xc + m[7] * (float)yr + m[8];
        float cw = fmaxf(fabsf(wc), 1e-8f);
        float dsda = fabsf(det) / (cw * cw * cw);
        float ld = logf(dsda + 1e-8f);
        const ushort_t one = f2bf(1.0f);
        short8 z = {0, 0, 0, 0, 0, 0, 0, 0};
        short8 sa = z; sa[0] = (short)f2bf(ld); sa[1] = (short)one;
        short8 sb = z; sb[0] = (short)one;
        *(short8*)&ha[pt * PADH + 48] = sa;
        *(short8*)&ha[pt * PADH + 56] = z;
        *(short8*)&hb[pt * PADH + 48] = sb;
        *(short8*)&hb[pt * PADH + 56] = z;
    }
    asm volatile("s_waitcnt lgkmcnt(0)" ::: "memory");

    f32x4 a1[3] = {{0.f,0.f,0.f,0.f},{0.f,0.f,0.f,0.f},{0.f,0.f,0.f,0.f}};
    #pragma unroll
    for (int ks = 0; ks < 2; ++ks) {
        short8 bf = *(const short8*)&ha[lo * PADH + ks * 32 + g8];
        #pragma unroll
        for (int mf = 0; mf < 3; ++mf) {
            short8 af = *(const short8*)&wA1[(mf * 16 + lo) * 64 + ks * 32 + g8];
            a1[mf] = __builtin_amdgcn_mfma_f32_16x16x32_bf16(af, bf, a1[mf], 0, 0, 0);
        }
    }
    #pragma unroll
    for (int mf = 0; mf < 3; ++mf) {
        short4v sv;
        #pragma unroll
        for (int j = 0; j < 4; ++j) sv[j] = (short)f2bf(fmaxf(a1[mf][j], 0.f));
        *(short4v*)&hb[lo * PADH + mf * 16 + (ln >> 4) * 4] = sv;
    }
    asm volatile("s_waitcnt lgkmcnt(0)" ::: "memory");

    f32x4 a2[3] = {{0.f,0.f,0.f,0.f},{0.f,0.f,0.f,0.f},{0.f,0.f,0.f,0.f}};
    #pragma unroll
    for (int ks = 0; ks < 2; ++ks) {
        short8 bf = *(const short8*)&hb[lo * PADH + ks * 32 + g8];
        #pragma unroll
        for (int mf = 0; mf < 3; ++mf) {
            short8 af = *(const short8*)&wA2[(mf * 16 + lo) * 64 + ks * 32 + g8];
            a2[mf] = __builtin_amdgcn_mfma_f32_16x16x32_bf16(af, bf, a2[mf], 0, 0, 0);
        }
    }
    #pragma unroll
    for (int mf = 0; mf < 3; ++mf) {
        short4v sv;
        #pragma unroll
        for (int j = 0; j < 4; ++j) sv[j] = (short)f2bf(fmaxf(a2[mf][j], 0.f));
        *(short4v*)&ha[lo * PADH + mf * 16 + (ln >> 4) * 4] = sv;
    }
    asm volatile("s_waitcnt lgkmcnt(0)" ::: "memory");

    f32x4 a3 = {0.f, 0.f, 0.f, 0.f};
    #pragma unroll
    for (int ks = 0; ks < 2; ++ks) {
        short8 bf = *(const short8*)&ha[lo * PADH + ks * 32 + g8];
        short8 af = *(const short8*)&wA3[lo * 64 + ks * 32 + g8];
        a3 = __builtin_amdgcn_mfma_f32_16x16x32_bf16(af, bf, a3, 0, 0, 0);
    }
    if (ln < 16) {
        int n = (t0 + lo) & (Nn - 1);
        int pos = yi[n];
        #pragma unroll
        for (int j = 0; j < 3; ++j)
            pvd[(size_t)(b * Pp + j) * HW + pos] = a3[j];
    }
}

// ---------------- out[b,c,pos] = sum_p pvd[b,p,pos] * xs[p,b,c,pos] ----------------
__global__ __launch_bounds__(256) void k_blend(const float4* __restrict__ xs,
                                               const float4* __restrict__ pvd,
                                               float4* __restrict__ out) {
    int i = blockIdx.x * 256 + threadIdx.x;   // over B*C*HW/4
    int pos4 = i & (HW / 4 - 1);
    int bc = i >> 14;
    int b = bc >> 6;
    float4 acc = make_float4(0.f, 0.f, 0.f, 0.f);
    #pragma unroll
    for (int p = 0; p < Pp; ++p) {
        float4 pv = pvd[(b * Pp + p) * (HW / 4) + pos4];
        float4 x = xs[p * (Bb * Cc * HW / 4) + i];
        acc.x += pv.x * x.x;
        acc.y += pv.y * x.y;
        acc.z += pv.z * x.z;
        acc.w += pv.w * x.w;
    }
    out[i] = acc;
}

extern "C" void kernel_launch(void* const* d_in, const int* in_sizes, int n_in,
                              void* d_out, int out_size, void* d_ws, size_t ws_size,
                              hipStream_t stream) {
    const float* xs        = (const float*)d_in[0];
    const float* mask      = (const float*)d_in[1];
    const int*   yi        = (const int*)d_in[2];
    const float* m         = (const float*)d_in[3];
    const float* ss_res_w  = (const float*)d_in[4];
    const float* ss_out_w  = (const float*)d_in[5];
    const float* feat_res_w= (const float*)d_in[6];
    const float* w1 = (const float*)d_in[7];
    const float* b1 = (const float*)d_in[8];
    const float* w2 = (const float*)d_in[9];
    const float* b2 = (const float*)d_in[10];
    const float* w3 = (const float*)d_in[11];
    const float* b3 = (const float*)d_in[12];

    // ws: wm f32 | pvd f32 | wB | wA | X (P,B,HW,64) | U | V | F (B,HW,64) | G  ~188MB
    float* wm  = (float*)d_ws;
    float* pvd = wm + HW;
    ushort_t* wB = (ushort_t*)(pvd + (size_t)Bb * Pp * HW);
    constexpr size_t RES_T = 12 * 9 * 64 * 64;     // 442368
    constexpr size_t OUT_T = 3 * 9 * 16 * 64;      // 27648
    constexpr size_t TRK_T = 4 * 9 * 48 * 64;      // 110592
    constexpr size_t MLP_T = 7168;
    constexpr size_t ZT = (size_t)Pp * Bb * HW * 64;   // 25165824
    ushort_t* wA = wB + RES_T + OUT_T + TRK_T;
    ushort_t* X = wA + MLP_T;
    ushort_t* U = X + ZT;
    ushort_t* V = U + ZT;
    ushort_t* F = V + ZT;
    ushort_t* G = F + (size_t)Bb * HW * 64;

    k_wm<<<HW / 256, 256, 0, stream>>>(mask, wm);
    k_wx_res  <<<RES_T / 256, 256, 0, stream>>>(ss_res_w, wB);
    k_wx_out  <<<OUT_T / 256, 256, 0, stream>>>(ss_out_w, wB + RES_T);
    k_wx_trunk<<<TRK_T / 256, 256, 0, stream>>>(feat_res_w, wB + RES_T + OUT_T);
    k_wx_mlp  <<<MLP_T / 256, 256, 0, stream>>>(w1, b1, w2, b2, w3, b3, wA);

    const dim3 gridP(Ww / TW, Hh / TH, Pp * Bb);   // (8, 32, 6)
    const dim3 gridT(Ww / TW, Hh / TH, Bb);        // (8, 32, 2)
    const int RS = 4 * 9 * 64 * 64;                // per-pyramid res weight stride
    const int OS = 9 * 16 * 64;                    // per-pyramid out weight stride

    k_xm<<<dim3(HW / 64, Pp * Bb), 256, 0, stream>>>(xs, mask, X);
    k_mconv<64, 0, false><<<gridP, 256, 0, stream>>>(X, wB,             RS, wm, nullptr, U);
    k_mconv<64, 1, false><<<gridP, 256, 0, stream>>>(U, wB + 1 * 36864, RS, wm, X,       V);
    k_mconv<64, 0, false><<<gridP, 256, 0, stream>>>(V, wB + 2 * 36864, RS, wm, nullptr, U);
    k_mconv<64, 1, false><<<gridP, 256, 0, stream>>>(U, wB + 3 * 36864, RS, wm, V,       V);
    k_mconv<16, 2, true ><<<gridP, 256, 0, stream>>>(V, wB + RES_T,     OS, wm, nullptr, F);

    const ushort_t* tw = wB + RES_T + OUT_T;
    k_mconv<48, 0, false><<<gridT, 256, 0, stream>>>(F, tw,             0, wm, nullptr, U);
    k_mconv<48, 1, false><<<gridT, 256, 0, stream>>>(U, tw + 1 * 27648, 0, wm, F,       G);
    k_mconv<48, 0, false><<<gridT, 256, 0, stream>>>(G, tw + 2 * 27648, 0, wm, nullptr, U);
    k_mconv<48, 1, false><<<gridT, 256, 0, stream>>>(U, tw + 3 * 27648, 0, wm, G,       G);

    k_zero<<<(Bb * Pp * HW / 4) / 256, 256, 0, stream>>>((float4*)pvd);
    k_gather_mlp<<<Bb * Nn / 64, 256, 0, stream>>>(F, G, yi, m,
        wA, wA + 3072, wA + 6144, pvd);
    k_blend<<<(Bb * Cc * HW / 4) / 256, 256, 0, stream>>>((const float4*)xs, (const float4*)pvd,
                                                          (float4*)d_out);
}